// Round 5
// baseline (166.673 us; speedup 1.0000x reference)
//
#include <hip/hip_runtime.h>
#include <hip/hip_bf16.h>
#include <stdint.h>

#define T_TOK 8192
#define D_IN  512
#define DINT  256
#define NE    8

typedef float f32x4 __attribute__((ext_vector_type(4)));
typedef short bf16x8 __attribute__((ext_vector_type(8)));
typedef unsigned short u16;
typedef unsigned short u16x4 __attribute__((ext_vector_type(4)));

// ws layout (bytes). NOTE: opair overlays xb+f1b (both fully consumed by fc1
// before fc2 writes opair; stream order guarantees safety, re-written each call).
#define WS_CNT   0
#define WS_BTOK  1024                      // int [NE][T_TOK]
#define WS_WP    263168                    // f32 [T_TOK*2]
#define WS_F2B   328704                    // bf16 fc2
#define WS_AA    2425856                   // bf16 act [16384][256]
#define WS_XB    10814464                  // bf16 x [8192][512]
#define WS_F1B   19203072                  // bf16 fc1
#define WS_OP    WS_XB                     // bf16 out_pairs [16384][512] (overlay)
// max end = 27,591,680 B (< 31.8MB proven)

typedef const __attribute__((address_space(1))) void* gptr_t;
typedef __attribute__((address_space(3))) void* lptr_t;
#define GLL16(g, s) __builtin_amdgcn_global_load_lds((gptr_t)(g), (lptr_t)(s), 16, 0, 0)

static __device__ __forceinline__ u16 f32_bf16(float f) {
    union { float f; uint32_t u; } v; v.f = f;
    uint32_t u = v.u;
    uint32_t r = (u + 0x7FFFu + ((u >> 16) & 1u)) >> 16;   // RTNE
    return (u16)r;
}
static __device__ __forceinline__ float bf16_f32(u16 h) {
    union { uint32_t u; float f; } v; v.u = ((uint32_t)h) << 16; return v.f;
}

// ---------------- 1. f32 -> bf16 of fc1, fc2 ----------------
__global__ __launch_bounds__(256) void cvt_kernel(
    const float* __restrict__ fc1, const float* __restrict__ fc2,
    u16* __restrict__ f1b, u16* __restrict__ f2b)
{
    const int N1 = NE * 2 * DINT * D_IN / 4;
    const int N2 = NE * D_IN * DINT / 4;
    const int total = N1 + N2;
    for (int i = blockIdx.x * 256 + threadIdx.x; i < total; i += gridDim.x * 256) {
        const float4* s; u16* d; int j;
        if (i < N1) { s = (const float4*)fc1; d = f1b; j = i; }
        else        { s = (const float4*)fc2; d = f2b; j = i - N1; }
        float4 v = s[j];
        u16x4 o;
        o.x = f32_bf16(v.x); o.y = f32_bf16(v.y);
        o.z = f32_bf16(v.z); o.w = f32_bf16(v.w);
        *(u16x4*)&d[(size_t)j * 4] = o;
    }
}

// ------- 2. gate: coalesced x staging (-> xb bf16), logits, top-2, buckets ----
__global__ __launch_bounds__(256) void gate_kernel(
    const float* __restrict__ x, const float* __restrict__ wg,
    int* __restrict__ cnt, int* __restrict__ btok, float* __restrict__ wpair,
    u16* __restrict__ xb)
{
    __shared__ float wgl[NE * D_IN];     // 16 KB
    __shared__ float xt[64][67];         // transposed chunk [col][row], 17.2 KB
    __shared__ float part[256 * 9];
    __shared__ int ecnt[NE];
    __shared__ int gbase[NE];

    const int tid = threadIdx.x;
    const int t0  = blockIdx.x * 64;
    const int tl  = tid & 63;
    const int kq  = tid >> 6;

    for (int i = tid; i < NE * D_IN; i += 256) wgl[i] = wg[i];
    if (tid < NE) ecnt[tid] = 0;

    float acc[NE];
#pragma unroll
    for (int e = 0; e < NE; e++) acc[e] = 0.f;

    for (int c = 0; c < 8; ++c) {
        __syncthreads();
#pragma unroll
        for (int i = 0; i < 4; ++i) {
            int idx = i * 256 + tid;           // 1024 float4 = 64 rows x 16 f4
            int row = idx >> 4, c4 = idx & 15;
            float4 v = *(const float4*)&x[(size_t)(t0 + row) * D_IN + c * 64 + c4 * 4];
            u16x4 o;
            o.x = f32_bf16(v.x); o.y = f32_bf16(v.y);
            o.z = f32_bf16(v.z); o.w = f32_bf16(v.w);
            *(u16x4*)&xb[(size_t)(t0 + row) * D_IN + c * 64 + c4 * 4] = o;
            xt[c4 * 4 + 0][row] = v.x; xt[c4 * 4 + 1][row] = v.y;
            xt[c4 * 4 + 2][row] = v.z; xt[c4 * 4 + 3][row] = v.w;
        }
        __syncthreads();
#pragma unroll
        for (int j = 0; j < 16; ++j) {
            float xv = xt[kq * 16 + j][tl];
#pragma unroll
            for (int e = 0; e < NE; e++)
                acc[e] = fmaf(xv, wgl[e * D_IN + c * 64 + kq * 16 + j], acc[e]);
        }
    }
#pragma unroll
    for (int e = 0; e < NE; e++) part[tid * 9 + e] = acc[e];
    __syncthreads();

    int i1 = 0, i2 = -1, lp1 = 0, lp2 = 0;
    if (tid < 64) {
        float s8[NE];
#pragma unroll
        for (int e = 0; e < NE; e++)
            s8[e] = part[tid * 9 + e] + part[(64 + tid) * 9 + e]
                  + part[(128 + tid) * 9 + e] + part[(192 + tid) * 9 + e];
        float m = s8[0];
#pragma unroll
        for (int e = 1; e < NE; e++) m = fmaxf(m, s8[e]);
        float p[NE], s = 0.f;
#pragma unroll
        for (int e = 0; e < NE; e++) { p[e] = expf(s8[e] - m); s += p[e]; }
        float inv = 1.f / s;
        float v1 = p[0];
#pragma unroll
        for (int e = 1; e < NE; e++) if (p[e] > v1) { v1 = p[e]; i1 = e; }
        float v2 = -1.f;
#pragma unroll
        for (int e = 0; e < NE; e++) if (e != i1 && p[e] > v2) { v2 = p[e]; i2 = e; }
        int t = t0 + tid;
        wpair[2 * t]     = v1 * inv;
        wpair[2 * t + 1] = v2 * inv;
        lp1 = atomicAdd(&ecnt[i1], 1);
        lp2 = atomicAdd(&ecnt[i2], 1);
    }
    __syncthreads();
    if (tid < NE) gbase[tid] = atomicAdd(&cnt[tid], ecnt[tid]);
    __syncthreads();
    if (tid < 64) {
        int t = t0 + tid;
        btok[i1 * T_TOK + gbase[i1] + lp1] = 2 * t;
        btok[i2 * T_TOK + gbase[i2] + lp2] = 2 * t + 1;
    }
}

// ---------------- 3. fc1 + GLU -> aact ----------------
// block 256thr/4 waves; tile M=64 x N=256 (y-quarter + matching gate-quarter);
// wave w owns local cols [w*64, w*64+64) as {y16,y16,g16,g16} frags.
// A LDS [m4][kgrp4][row16] sub-tiled, B LDS [grp16][kgrp4][col16]: all fragment
// reads are 64 consecutive 16B lanes -> conflict-free; GLL16 dests linear.
__global__ __launch_bounds__(256, 4) void fc1_kernel(
    const u16* __restrict__ xb, const u16* __restrict__ f1b,
    const int* __restrict__ cnt, const int* __restrict__ btok,
    u16* __restrict__ aact)
{
    __shared__ __align__(16) u16 abuf[2][2048];   // 2 x 4KB
    __shared__ __align__(16) u16 bbuf[2][8192];   // 2 x 16KB (act overlay)

    const int bid = blockIdx.x;
    const int e   = bid & 7;
    const int sub = bid >> 3;
    const int ns  = sub & 1;
    const int mt0 = sub >> 1;                     // 0..31
    const int n   = cnt[e];

    const int tid = threadIdx.x;
    const int wv  = tid >> 6, lane = tid & 63;
    const int l15 = lane & 15, lhi = lane >> 4;

    const u16* w1 = f1b + (size_t)e * 512 * 512;
    const int g0 = wv * 4;
    const int rb0 = (g0 + 0 < 8) ? (ns * 128 + (g0 + 0) * 16) : (256 + ns * 128 + (g0 - 8) * 16);
    const int rb1 = (g0 + 1 < 8) ? (ns * 128 + (g0 + 1) * 16) : (256 + ns * 128 + (g0 - 7) * 16);
    const int rb2 = (g0 + 2 < 8) ? (ns * 128 + (g0 + 2) * 16) : (256 + ns * 128 + (g0 - 6) * 16);
    const int rb3 = (g0 + 3 < 8) ? (ns * 128 + (g0 + 3) * 16) : (256 + ns * 128 + (g0 - 5) * 16);
    const u16* bsrc0 = w1 + (size_t)(rb0 + l15) * 512 + lhi * 8;
    const u16* bsrc1 = w1 + (size_t)(rb1 + l15) * 512 + lhi * 8;
    const u16* bsrc2 = w1 + (size_t)(rb2 + l15) * 512 + lhi * 8;
    const u16* bsrc3 = w1 + (size_t)(rb3 + l15) * 512 + lhi * 8;

#define STG1(BUF, K0) {                                              \
    GLL16(asrc  + (K0), &abuf[BUF][wv * 512]);                       \
    GLL16(bsrc0 + (K0), &bbuf[BUF][(g0 + 0) * 512]);                 \
    GLL16(bsrc1 + (K0), &bbuf[BUF][(g0 + 1) * 512]);                 \
    GLL16(bsrc2 + (K0), &bbuf[BUF][(g0 + 2) * 512]);                 \
    GLL16(bsrc3 + (K0), &bbuf[BUF][(g0 + 3) * 512]); }

    for (int mt = mt0; mt * 64 < n; mt += 32) {
        const int row0  = mt * 64;
        const int nrows = (n - row0 < 64) ? (n - row0) : 64;
        __syncthreads();                          // LDS reuse guard across tiles

        // wave wv stages rows [wv*16, wv*16+16): lane -> (row=l15, kgrp=lhi)
        int ar = wv * 16 + l15;
        int arow = row0 + ((ar < nrows) ? ar : 0);
        const u16* asrc = xb + (size_t)(btok[e * T_TOK + arow] >> 1) * 512 + lhi * 8;

        f32x4 acc[4][4];
#pragma unroll
        for (int m = 0; m < 4; m++)
#pragma unroll
            for (int nb = 0; nb < 4; nb++) acc[m][nb] = (f32x4)0.f;

        STG1(0, 0);
#pragma unroll
        for (int ks = 0; ks < 16; ks++) {
            const int k0 = ks * 32, cur = ks & 1;
            __syncthreads();                      // buf[cur] staged + prev reads done
            if (ks < 15) STG1(cur ^ 1, k0 + 32);
            bf16x8 a[4], b[4];
#pragma unroll
            for (int m = 0; m < 4; m++)
                a[m] = *(const bf16x8*)&abuf[cur][m * 512 + lane * 8];
            b[0] = *(const bf16x8*)&bbuf[cur][(wv * 2 + 0) * 512 + lane * 8];
            b[1] = *(const bf16x8*)&bbuf[cur][(wv * 2 + 1) * 512 + lane * 8];
            b[2] = *(const bf16x8*)&bbuf[cur][(8 + wv * 2) * 512 + lane * 8];
            b[3] = *(const bf16x8*)&bbuf[cur][(9 + wv * 2) * 512 + lane * 8];
#pragma unroll
            for (int m = 0; m < 4; m++)
#pragma unroll
                for (int nb = 0; nb < 4; nb++)
                    acc[m][nb] = __builtin_amdgcn_mfma_f32_16x16x32_bf16(
                        a[m], b[nb], acc[m][nb], 0, 0, 0);
        }

        __syncthreads();                          // bbuf reads done -> act overlay
        u16* act = &bbuf[0][0];                   // [64][144] u16, 18.4KB
#pragma unroll
        for (int m = 0; m < 4; m++) {
#pragma unroll
            for (int nb = 0; nb < 2; nb++) {
#pragma unroll
                for (int r = 0; r < 4; r++) {
                    float y = acc[m][nb][r];
                    float g = acc[m][nb + 2][r];
                    float v = y * g / (1.f + __expf(-g));
                    int row = m * 16 + lhi * 4 + r;
                    int col = wv * 32 + nb * 16 + l15;
                    act[row * 144 + col] = f32_bf16(v);
                }
            }
        }
        __syncthreads();
        // coalesced store: thread -> (row=tid>>2, 64B segment tid&3)
        int orow = tid >> 2, seg = tid & 3;
        if (orow < nrows) {
            int slot = btok[e * T_TOK + row0 + orow];
            u16* dst = aact + (size_t)slot * 256 + ns * 128 + seg * 32;
#pragma unroll
            for (int q = 0; q < 4; q++)
                *(bf16x8*)&dst[q * 8] = *(const bf16x8*)&act[orow * 144 + seg * 32 + q * 8];
        }
    }
#undef STG1
}

// ---------------- 4. fc2 -> opair ----------------
__global__ __launch_bounds__(256, 4) void fc2_kernel(
    const u16* __restrict__ aact, const u16* __restrict__ f2b,
    const int* __restrict__ cnt, const int* __restrict__ btok,
    u16* __restrict__ opair)
{
    __shared__ __align__(16) u16 abuf[2][2048];
    __shared__ __align__(16) u16 bbuf[2][8192];

    const int bid = blockIdx.x;
    const int e   = bid & 7;
    const int sub = bid >> 3;
    const int ns  = sub & 1;
    const int mt0 = sub >> 1;
    const int n   = cnt[e];

    const int tid = threadIdx.x;
    const int wv  = tid >> 6, lane = tid & 63;
    const int l15 = lane & 15, lhi = lane >> 4;

    const u16* w2 = f2b + (size_t)e * D_IN * DINT;
    const u16* bsrc0 = w2 + (size_t)(ns * 256 + (wv * 4 + 0) * 16 + l15) * DINT + lhi * 8;
    const u16* bsrc1 = bsrc0 + (size_t)16 * DINT;
    const u16* bsrc2 = bsrc0 + (size_t)32 * DINT;
    const u16* bsrc3 = bsrc0 + (size_t)48 * DINT;

#define STG2(BUF, K0) {                                              \
    GLL16(asrc  + (K0), &abuf[BUF][wv * 512]);                       \
    GLL16(bsrc0 + (K0), &bbuf[BUF][(wv * 4 + 0) * 512]);             \
    GLL16(bsrc1 + (K0), &bbuf[BUF][(wv * 4 + 1) * 512]);             \
    GLL16(bsrc2 + (K0), &bbuf[BUF][(wv * 4 + 2) * 512]);             \
    GLL16(bsrc3 + (K0), &bbuf[BUF][(wv * 4 + 3) * 512]); }

    for (int mt = mt0; mt * 64 < n; mt += 32) {
        const int row0  = mt * 64;
        const int nrows = (n - row0 < 64) ? (n - row0) : 64;
        __syncthreads();

        int ar = wv * 16 + l15;
        int arow = row0 + ((ar < nrows) ? ar : 0);
        const u16* asrc = aact + (size_t)btok[e * T_TOK + arow] * DINT + lhi * 8;

        f32x4 acc[4][4];
#pragma unroll
        for (int m = 0; m < 4; m++)
#pragma unroll
            for (int nb = 0; nb < 4; nb++) acc[m][nb] = (f32x4)0.f;

        STG2(0, 0);
#pragma unroll
        for (int ks = 0; ks < 8; ks++) {
            const int k0 = ks * 32, cur = ks & 1;
            __syncthreads();
            if (ks < 7) STG2(cur ^ 1, k0 + 32);
            bf16x8 a[4], b[4];
#pragma unroll
            for (int m = 0; m < 4; m++)
                a[m] = *(const bf16x8*)&abuf[cur][m * 512 + lane * 8];
#pragma unroll
            for (int nb = 0; nb < 4; nb++)
                b[nb] = *(const bf16x8*)&bbuf[cur][(wv * 4 + nb) * 512 + lane * 8];
#pragma unroll
            for (int m = 0; m < 4; m++)
#pragma unroll
                for (int nb = 0; nb < 4; nb++)
                    acc[m][nb] = __builtin_amdgcn_mfma_f32_16x16x32_bf16(
                        a[m], b[nb], acc[m][nb], 0, 0, 0);
        }

#pragma unroll
        for (int m = 0; m < 4; m++) {
#pragma unroll
            for (int r = 0; r < 4; r++) {
                int row = m * 16 + lhi * 4 + r;
                if (row < nrows) {
                    int slot = btok[e * T_TOK + row0 + row];
                    u16* oo = opair + (size_t)slot * D_IN + ns * 256 + wv * 64 + l15;
#pragma unroll
                    for (int nb = 0; nb < 4; nb++)
                        oo[nb * 16] = f32_bf16(acc[m][nb][r]);
                }
            }
        }
    }
#undef STG2
}

// ---------------- 5. combine ----------------
__global__ __launch_bounds__(256) void combine_kernel(
    const u16* __restrict__ opair, const float* __restrict__ wpair,
    float* __restrict__ out)
{
    int idx = blockIdx.x * 256 + threadIdx.x;
    int t  = idx >> 6;
    int c8 = (idx & 63) * 8;
    float w0 = wpair[2 * t], w1 = wpair[2 * t + 1];
    bf16x8 a = *(const bf16x8*)&opair[(size_t)(2 * t) * D_IN + c8];
    bf16x8 b = *(const bf16x8*)&opair[(size_t)(2 * t + 1) * D_IN + c8];
    float4 o0, o1;
#pragma unroll
    for (int j = 0; j < 4; j++) {
        o0[j] = w0 * bf16_f32((u16)a[j])     + w1 * bf16_f32((u16)b[j]);
        o1[j] = w0 * bf16_f32((u16)a[j + 4]) + w1 * bf16_f32((u16)b[j + 4]);
    }
    float* orow = out + (size_t)t * D_IN + c8;
    *(float4*)orow = o0;
    *(float4*)(orow + 4) = o1;
}

// ---------------- launch ----------------
extern "C" void kernel_launch(void* const* d_in, const int* in_sizes, int n_in,
                              void* d_out, int out_size, void* d_ws, size_t ws_size,
                              hipStream_t stream) {
    const float* x   = (const float*)d_in[0];
    const float* wg  = (const float*)d_in[1];
    const float* fc1 = (const float*)d_in[2];
    const float* fc2 = (const float*)d_in[3];
    float* out = (float*)d_out;
    char* ws = (char*)d_ws;

    int*   cnt   = (int*)(ws + WS_CNT);
    int*   btok  = (int*)(ws + WS_BTOK);
    float* wpair = (float*)(ws + WS_WP);
    u16*   f1b   = (u16*)(ws + WS_F1B);
    u16*   f2b   = (u16*)(ws + WS_F2B);
    u16*   xb    = (u16*)(ws + WS_XB);
    u16*   aact  = (u16*)(ws + WS_AA);
    u16*   opair = (u16*)(ws + WS_OP);

    hipMemsetAsync(cnt, 0, 1024, stream);

    cvt_kernel<<<1024, 256, 0, stream>>>(fc1, fc2, f1b, f2b);
    gate_kernel<<<T_TOK / 64, 256, 0, stream>>>(x, wg, cnt, btok, wpair, xb);
    fc1_kernel<<<512, 256, 0, stream>>>(xb, f1b, cnt, btok, aact);
    fc2_kernel<<<512, 256, 0, stream>>>(aact, f2b, cnt, btok, opair);
    combine_kernel<<<T_TOK * (D_IN / 8) / 256, 256, 0, stream>>>(opair, wpair, out);
}

// Round 6
// 131.785 us; speedup vs baseline: 1.2647x; 1.2647x over previous
//
#include <hip/hip_runtime.h>
#include <hip/hip_bf16.h>
#include <stdint.h>

#define T_TOK 8192
#define D_IN  512
#define DINT  256
#define NE    8

typedef float f32x4 __attribute__((ext_vector_type(4)));
typedef short bf16x8 __attribute__((ext_vector_type(8)));
typedef unsigned short u16;
typedef unsigned short u16x4 __attribute__((ext_vector_type(4)));

// ws layout (bytes). opair overlays xb+f1b (both fully consumed by fc1 before
// fc2 writes opair; stream order guarantees safety, re-written every call).
#define WS_CNT   0
#define WS_BTOK  1024                      // int [NE][T_TOK]
#define WS_WP    263168                    // f32 [T_TOK*2]
#define WS_F2B   328704                    // bf16 fc2
#define WS_AA    2425856                   // bf16 act [16384][256]
#define WS_XB    10814464                  // bf16 x [8192][512]
#define WS_F1B   19203072                  // bf16 fc1
#define WS_OP    WS_XB                     // bf16 out_pairs [16384][512] overlay

typedef const __attribute__((address_space(1))) void* gptr_t;
typedef __attribute__((address_space(3))) void* lptr_t;
#define GLL16(g, s) __builtin_amdgcn_global_load_lds((gptr_t)(g), (lptr_t)(s), 16, 0, 0)

static __device__ __forceinline__ u16 f32_bf16(float f) {
    union { float f; uint32_t u; } v; v.f = f;
    uint32_t u = v.u;
    uint32_t r = (u + 0x7FFFu + ((u >> 16) & 1u)) >> 16;   // RTNE
    return (u16)r;
}
static __device__ __forceinline__ float bf16_f32(u16 h) {
    union { uint32_t u; float f; } v; v.u = ((uint32_t)h) << 16; return v.f;
}

// ---------------- 1. f32 -> bf16 of fc1, fc2 ----------------
__global__ __launch_bounds__(256) void cvt_kernel(
    const float* __restrict__ fc1, const float* __restrict__ fc2,
    u16* __restrict__ f1b, u16* __restrict__ f2b)
{
    const int N1 = NE * 2 * DINT * D_IN / 4;
    const int N2 = NE * D_IN * DINT / 4;
    const int total = N1 + N2;
    for (int i = blockIdx.x * 256 + threadIdx.x; i < total; i += gridDim.x * 256) {
        const float4* s; u16* d; int j;
        if (i < N1) { s = (const float4*)fc1; d = f1b; j = i; }
        else        { s = (const float4*)fc2; d = f2b; j = i - N1; }
        float4 v = s[j];
        u16x4 o;
        o.x = f32_bf16(v.x); o.y = f32_bf16(v.y);
        o.z = f32_bf16(v.z); o.w = f32_bf16(v.w);
        *(u16x4*)&d[(size_t)j * 4] = o;
    }
}

// ------- 2. gate: coalesced x staging (-> xb bf16), logits, top-2, buckets ----
__global__ __launch_bounds__(256) void gate_kernel(
    const float* __restrict__ x, const float* __restrict__ wg,
    int* __restrict__ cnt, int* __restrict__ btok, float* __restrict__ wpair,
    u16* __restrict__ xb)
{
    __shared__ float wgl[NE * D_IN];
    __shared__ float xt[64][67];
    __shared__ float part[256 * 9];
    __shared__ int ecnt[NE];
    __shared__ int gbase[NE];

    const int tid = threadIdx.x;
    const int t0  = blockIdx.x * 64;
    const int tl  = tid & 63;
    const int kq  = tid >> 6;

    for (int i = tid; i < NE * D_IN; i += 256) wgl[i] = wg[i];
    if (tid < NE) ecnt[tid] = 0;

    float acc[NE];
#pragma unroll
    for (int e = 0; e < NE; e++) acc[e] = 0.f;

    for (int c = 0; c < 8; ++c) {
        __syncthreads();
#pragma unroll
        for (int i = 0; i < 4; ++i) {
            int idx = i * 256 + tid;
            int row = idx >> 4, c4 = idx & 15;
            float4 v = *(const float4*)&x[(size_t)(t0 + row) * D_IN + c * 64 + c4 * 4];
            u16x4 o;
            o.x = f32_bf16(v.x); o.y = f32_bf16(v.y);
            o.z = f32_bf16(v.z); o.w = f32_bf16(v.w);
            *(u16x4*)&xb[(size_t)(t0 + row) * D_IN + c * 64 + c4 * 4] = o;
            xt[c4 * 4 + 0][row] = v.x; xt[c4 * 4 + 1][row] = v.y;
            xt[c4 * 4 + 2][row] = v.z; xt[c4 * 4 + 3][row] = v.w;
        }
        __syncthreads();
#pragma unroll
        for (int j = 0; j < 16; ++j) {
            float xv = xt[kq * 16 + j][tl];
#pragma unroll
            for (int e = 0; e < NE; e++)
                acc[e] = fmaf(xv, wgl[e * D_IN + c * 64 + kq * 16 + j], acc[e]);
        }
    }
#pragma unroll
    for (int e = 0; e < NE; e++) part[tid * 9 + e] = acc[e];
    __syncthreads();

    int i1 = 0, i2 = -1, lp1 = 0, lp2 = 0;
    if (tid < 64) {
        float s8[NE];
#pragma unroll
        for (int e = 0; e < NE; e++)
            s8[e] = part[tid * 9 + e] + part[(64 + tid) * 9 + e]
                  + part[(128 + tid) * 9 + e] + part[(192 + tid) * 9 + e];
        float m = s8[0];
#pragma unroll
        for (int e = 1; e < NE; e++) m = fmaxf(m, s8[e]);
        float p[NE], s = 0.f;
#pragma unroll
        for (int e = 0; e < NE; e++) { p[e] = expf(s8[e] - m); s += p[e]; }
        float inv = 1.f / s;
        float v1 = p[0];
#pragma unroll
        for (int e = 1; e < NE; e++) if (p[e] > v1) { v1 = p[e]; i1 = e; }
        float v2 = -1.f;
#pragma unroll
        for (int e = 0; e < NE; e++) if (e != i1 && p[e] > v2) { v2 = p[e]; i2 = e; }
        int t = t0 + tid;
        wpair[2 * t]     = v1 * inv;
        wpair[2 * t + 1] = v2 * inv;
        lp1 = atomicAdd(&ecnt[i1], 1);
        lp2 = atomicAdd(&ecnt[i2], 1);
    }
    __syncthreads();
    if (tid < NE) gbase[tid] = atomicAdd(&cnt[tid], ecnt[tid]);
    __syncthreads();
    if (tid < 64) {
        int t = t0 + tid;
        btok[i1 * T_TOK + gbase[i1] + lp1] = 2 * t;
        btok[i2 * T_TOK + gbase[i2] + lp2] = 2 * t + 1;
    }
}

// ---------------- 3. fc1 + GLU -> aact ----------------
// grid 1024 = e(8) x ns(8) x mc(16); block 256 (4 waves).
// Block stages its ENTIRE fc1 slice (y rows [ns*32,+32) + gate rows
// [256+ns*32,+32), 64KB) into LDS once via GLL16 (pre-swizzled source ->
// subtiled [g][kg][lane][16B], conflict-free b128 reads). ONE barrier.
// Then each wave independently streams 32 token-rows x 64 cols; NO barriers.
__global__ __launch_bounds__(256, 4) void fc1_kernel(
    const u16* __restrict__ xb, const u16* __restrict__ f1b,
    const int* __restrict__ cnt, const int* __restrict__ btok,
    u16* __restrict__ aact)
{
    __shared__ __align__(16) u16 bsl[4 * 16 * 512];   // 64 KB

    const int bid = blockIdx.x;
    const int e   = bid & 7;
    const int ns  = (bid >> 3) & 7;
    const int mc  = bid >> 6;                          // 0..15
    const int n   = cnt[e];

    const int tid = threadIdx.x;
    const int wv  = tid >> 6, lane = tid & 63;
    const int l15 = lane & 15, lhi = lane >> 4;

    // stage: wave wv owns b-group g=wv (16 fc1-rows x 512 K)
    {
        const int nr0 = (wv < 2) ? (ns * 32 + wv * 16)
                                 : (256 + ns * 32 + (wv - 2) * 16);
        const u16* src = f1b + (size_t)e * 512 * 512 + (size_t)(nr0 + l15) * 512 + lhi * 8;
#pragma unroll
        for (int kg = 0; kg < 16; ++kg)
            GLL16(src + kg * 32, &bsl[(wv * 16 + kg) * 512]);
    }
    __syncthreads();

    for (int row0 = mc * 128; row0 < n; row0 += 2048) {
        const int rbase = row0 + wv * 32;
        int r0 = rbase + l15;       if (r0 >= n) r0 = n - 1;
        int r1 = rbase + 16 + l15;  if (r1 >= n) r1 = n - 1;
        const int t0 = btok[e * T_TOK + r0];
        const int t1 = btok[e * T_TOK + r1];
        const u16* a0p = xb + (size_t)(t0 >> 1) * D_IN + lhi * 8;
        const u16* a1p = xb + (size_t)(t1 >> 1) * D_IN + lhi * 8;

        f32x4 acc[2][4];
#pragma unroll
        for (int m = 0; m < 2; m++)
#pragma unroll
            for (int g = 0; g < 4; g++) acc[m][g] = (f32x4)0.f;

#pragma unroll
        for (int kg = 0; kg < 16; ++kg) {
            bf16x8 a0 = *(const bf16x8*)(a0p + kg * 32);
            bf16x8 a1 = *(const bf16x8*)(a1p + kg * 32);
#pragma unroll
            for (int g = 0; g < 4; ++g) {
                bf16x8 b = *(const bf16x8*)&bsl[(g * 16 + kg) * 512 + lane * 8];
                acc[0][g] = __builtin_amdgcn_mfma_f32_16x16x32_bf16(a0, b, acc[0][g], 0, 0, 0);
                acc[1][g] = __builtin_amdgcn_mfma_f32_16x16x32_bf16(a1, b, acc[1][g], 0, 0, 0);
            }
        }

        // GLU + store: C frag (col=l15, row=lhi*4+j); slot via shfl
#pragma unroll
        for (int m = 0; m < 2; ++m) {
            int tm = (m == 0) ? t0 : t1;
#pragma unroll
            for (int j = 0; j < 4; ++j) {
                int rr = rbase + m * 16 + lhi * 4 + j;
                int slot = __shfl(tm, lhi * 4 + j);
                if (rr < n) {
                    u16* dst = aact + (size_t)slot * DINT + ns * 32 + l15;
#pragma unroll
                    for (int q = 0; q < 2; ++q) {
                        float y = acc[m][q][j], g = acc[m][q + 2][j];
                        float v = y * g / (1.f + __expf(-g));
                        dst[q * 16] = f32_bf16(v);
                    }
                }
            }
        }
    }
}

// ---------------- 4. fc2 -> opair ----------------
// grid 1024 = e(8) x ns(8: 64 out-cols) x mc(16); slice 64x256 = 32KB LDS.
__global__ __launch_bounds__(256, 4) void fc2_kernel(
    const u16* __restrict__ aact, const u16* __restrict__ f2b,
    const int* __restrict__ cnt, const int* __restrict__ btok,
    u16* __restrict__ opair)
{
    __shared__ __align__(16) u16 bsl[4 * 8 * 512];    // 32 KB

    const int bid = blockIdx.x;
    const int e   = bid & 7;
    const int ns  = (bid >> 3) & 7;
    const int mc  = bid >> 6;
    const int n   = cnt[e];

    const int tid = threadIdx.x;
    const int wv  = tid >> 6, lane = tid & 63;
    const int l15 = lane & 15, lhi = lane >> 4;

    {
        const int nr0 = ns * 64 + wv * 16;
        const u16* src = f2b + (size_t)e * D_IN * DINT + (size_t)(nr0 + l15) * DINT + lhi * 8;
#pragma unroll
        for (int kg = 0; kg < 8; ++kg)
            GLL16(src + kg * 32, &bsl[(wv * 8 + kg) * 512]);
    }
    __syncthreads();

    for (int row0 = mc * 128; row0 < n; row0 += 2048) {
        const int rbase = row0 + wv * 32;
        int r0 = rbase + l15;       if (r0 >= n) r0 = n - 1;
        int r1 = rbase + 16 + l15;  if (r1 >= n) r1 = n - 1;
        const int t0 = btok[e * T_TOK + r0];
        const int t1 = btok[e * T_TOK + r1];
        const u16* a0p = aact + (size_t)t0 * DINT + lhi * 8;
        const u16* a1p = aact + (size_t)t1 * DINT + lhi * 8;

        f32x4 acc[2][4];
#pragma unroll
        for (int m = 0; m < 2; m++)
#pragma unroll
            for (int g = 0; g < 4; g++) acc[m][g] = (f32x4)0.f;

#pragma unroll
        for (int kg = 0; kg < 8; ++kg) {
            bf16x8 a0 = *(const bf16x8*)(a0p + kg * 32);
            bf16x8 a1 = *(const bf16x8*)(a1p + kg * 32);
#pragma unroll
            for (int g = 0; g < 4; ++g) {
                bf16x8 b = *(const bf16x8*)&bsl[(g * 8 + kg) * 512 + lane * 8];
                acc[0][g] = __builtin_amdgcn_mfma_f32_16x16x32_bf16(a0, b, acc[0][g], 0, 0, 0);
                acc[1][g] = __builtin_amdgcn_mfma_f32_16x16x32_bf16(a1, b, acc[1][g], 0, 0, 0);
            }
        }

#pragma unroll
        for (int m = 0; m < 2; ++m) {
            int tm = (m == 0) ? t0 : t1;
#pragma unroll
            for (int j = 0; j < 4; ++j) {
                int rr = rbase + m * 16 + lhi * 4 + j;
                int slot = __shfl(tm, lhi * 4 + j);
                if (rr < n) {
                    u16* dst = opair + (size_t)slot * D_IN + ns * 64 + l15;
#pragma unroll
                    for (int g = 0; g < 4; ++g)
                        dst[g * 16] = f32_bf16(acc[m][g][j]);
                }
            }
        }
    }
}

// ---------------- 5. combine ----------------
__global__ __launch_bounds__(256) void combine_kernel(
    const u16* __restrict__ opair, const float* __restrict__ wpair,
    float* __restrict__ out)
{
    int idx = blockIdx.x * 256 + threadIdx.x;
    int t  = idx >> 6;
    int c8 = (idx & 63) * 8;
    float w0 = wpair[2 * t], w1 = wpair[2 * t + 1];
    bf16x8 a = *(const bf16x8*)&opair[(size_t)(2 * t) * D_IN + c8];
    bf16x8 b = *(const bf16x8*)&opair[(size_t)(2 * t + 1) * D_IN + c8];
    float4 o0, o1;
#pragma unroll
    for (int j = 0; j < 4; j++) {
        o0[j] = w0 * bf16_f32((u16)a[j])     + w1 * bf16_f32((u16)b[j]);
        o1[j] = w0 * bf16_f32((u16)a[j + 4]) + w1 * bf16_f32((u16)b[j + 4]);
    }
    float* orow = out + (size_t)t * D_IN + c8;
    *(float4*)orow = o0;
    *(float4*)(orow + 4) = o1;
}

// ---------------- launch ----------------
extern "C" void kernel_launch(void* const* d_in, const int* in_sizes, int n_in,
                              void* d_out, int out_size, void* d_ws, size_t ws_size,
                              hipStream_t stream) {
    const float* x   = (const float*)d_in[0];
    const float* wg  = (const float*)d_in[1];
    const float* fc1 = (const float*)d_in[2];
    const float* fc2 = (const float*)d_in[3];
    float* out = (float*)d_out;
    char* ws = (char*)d_ws;

    int*   cnt   = (int*)(ws + WS_CNT);
    int*   btok  = (int*)(ws + WS_BTOK);
    float* wpair = (float*)(ws + WS_WP);
    u16*   f1b   = (u16*)(ws + WS_F1B);
    u16*   f2b   = (u16*)(ws + WS_F2B);
    u16*   xb    = (u16*)(ws + WS_XB);
    u16*   aact  = (u16*)(ws + WS_AA);
    u16*   opair = (u16*)(ws + WS_OP);

    hipMemsetAsync(cnt, 0, 1024, stream);

    cvt_kernel<<<1024, 256, 0, stream>>>(fc1, fc2, f1b, f2b);
    gate_kernel<<<T_TOK / 64, 256, 0, stream>>>(x, wg, cnt, btok, wpair, xb);
    fc1_kernel<<<1024, 256, 0, stream>>>(xb, f1b, cnt, btok, aact);
    fc2_kernel<<<1024, 256, 0, stream>>>(aact, f2b, cnt, btok, opair);
    combine_kernel<<<T_TOK * (D_IN / 8) / 256, 256, 0, stream>>>(opair, wpair, out);
}

// Round 7
// 116.808 us; speedup vs baseline: 1.4269x; 1.1282x over previous
//
#include <hip/hip_runtime.h>
#include <hip/hip_bf16.h>
#include <stdint.h>

#define T_TOK 8192
#define D_IN  512
#define DINT  256
#define NE    8

typedef float f32x4 __attribute__((ext_vector_type(4)));
typedef short bf16x8 __attribute__((ext_vector_type(8)));
typedef unsigned short u16;
typedef unsigned short u16x4 __attribute__((ext_vector_type(4)));

// ws layout (bytes). og overlays xg (xg fully consumed by fc1 before fc2
// writes og; stream order guarantees safety; all buffers rewritten per call).
#define WS_CNT   0                // int[8]            (1024 B reserved)
#define WS_POS   1024             // int[16384]        -> ends 66560
#define WS_WP    66560            // f32[16384]        -> ends 132096
#define WS_BT    132096           // u16[8][8192]      -> ends 263168
#define WS_F2B   263168           // bf16 fc2 (2MB)    -> ends 2360320
#define WS_AA    2360320          // bf16 act [16384][256] (8MB) -> 10748928
#define WS_F1B   10748928         // bf16 fc1 (4MB)    -> ends 14943232
#define WS_XG    14943232         // bf16 xg [16384][512] (16MB) -> 31720448
#define WS_OG    WS_XG            // bf16 og [16384][512] overlay

typedef const __attribute__((address_space(1))) void* gptr_t;
typedef __attribute__((address_space(3))) void* lptr_t;
#define GLL16(g, s) __builtin_amdgcn_global_load_lds((gptr_t)(g), (lptr_t)(s), 16, 0, 0)

static __device__ __forceinline__ u16 f32_bf16(float f) {
    union { float f; uint32_t u; } v; v.f = f;
    uint32_t u = v.u;
    uint32_t r = (u + 0x7FFFu + ((u >> 16) & 1u)) >> 16;   // RTNE
    return (u16)r;
}
static __device__ __forceinline__ float bf16_f32(u16 h) {
    union { uint32_t u; float f; } v; v.u = ((uint32_t)h) << 16; return v.f;
}
static __device__ __forceinline__ int prefix_base(const int* cnt, int e) {
    int b = 0;
    for (int i = 0; i < e; ++i) b += cnt[i];
    return b;
}

// ---------------- 1. f32 -> bf16 of fc1, fc2 ----------------
__global__ __launch_bounds__(256) void cvt_kernel(
    const float* __restrict__ fc1, const float* __restrict__ fc2,
    u16* __restrict__ f1b, u16* __restrict__ f2b)
{
    const int N1 = NE * 2 * DINT * D_IN / 4;
    const int N2 = NE * D_IN * DINT / 4;
    const int total = N1 + N2;
    for (int i = blockIdx.x * 256 + threadIdx.x; i < total; i += gridDim.x * 256) {
        const float4* s; u16* d; int j;
        if (i < N1) { s = (const float4*)fc1; d = f1b; j = i; }
        else        { s = (const float4*)fc2; d = f2b; j = i - N1; }
        float4 v = s[j];
        u16x4 o;
        o.x = f32_bf16(v.x); o.y = f32_bf16(v.y);
        o.z = f32_bf16(v.z); o.w = f32_bf16(v.w);
        *(u16x4*)&d[(size_t)j * 4] = o;
    }
}

// ---------------- 2. gate: logits, softmax, top-2, buckets ----------------
__global__ __launch_bounds__(256) void gate_kernel(
    const float* __restrict__ x, const float* __restrict__ wg,
    int* __restrict__ cnt, u16* __restrict__ bt, float* __restrict__ wpair)
{
    __shared__ float wgl[NE * D_IN];
    __shared__ float xt[64][67];
    __shared__ float part[256 * 9];
    __shared__ int ecnt[NE];
    __shared__ int gbase[NE];

    const int tid = threadIdx.x;
    const int t0  = blockIdx.x * 64;
    const int tl  = tid & 63;
    const int kq  = tid >> 6;

    for (int i = tid; i < NE * D_IN; i += 256) wgl[i] = wg[i];
    if (tid < NE) ecnt[tid] = 0;

    float acc[NE];
#pragma unroll
    for (int e = 0; e < NE; e++) acc[e] = 0.f;

    for (int c = 0; c < 8; ++c) {
        __syncthreads();
#pragma unroll
        for (int i = 0; i < 4; ++i) {
            int idx = i * 256 + tid;
            int row = idx >> 4, c4 = idx & 15;
            float4 v = *(const float4*)&x[(size_t)(t0 + row) * D_IN + c * 64 + c4 * 4];
            xt[c4 * 4 + 0][row] = v.x; xt[c4 * 4 + 1][row] = v.y;
            xt[c4 * 4 + 2][row] = v.z; xt[c4 * 4 + 3][row] = v.w;
        }
        __syncthreads();
#pragma unroll
        for (int j = 0; j < 16; ++j) {
            float xv = xt[kq * 16 + j][tl];
#pragma unroll
            for (int e = 0; e < NE; e++)
                acc[e] = fmaf(xv, wgl[e * D_IN + c * 64 + kq * 16 + j], acc[e]);
        }
    }
#pragma unroll
    for (int e = 0; e < NE; e++) part[tid * 9 + e] = acc[e];
    __syncthreads();

    int i1 = 0, i2 = -1, lp1 = 0, lp2 = 0;
    if (tid < 64) {
        float s8[NE];
#pragma unroll
        for (int e = 0; e < NE; e++)
            s8[e] = part[tid * 9 + e] + part[(64 + tid) * 9 + e]
                  + part[(128 + tid) * 9 + e] + part[(192 + tid) * 9 + e];
        float m = s8[0];
#pragma unroll
        for (int e = 1; e < NE; e++) m = fmaxf(m, s8[e]);
        float p[NE], s = 0.f;
#pragma unroll
        for (int e = 0; e < NE; e++) { p[e] = expf(s8[e] - m); s += p[e]; }
        float inv = 1.f / s;
        float v1 = p[0];
#pragma unroll
        for (int e = 1; e < NE; e++) if (p[e] > v1) { v1 = p[e]; i1 = e; }
        float v2 = -1.f;
#pragma unroll
        for (int e = 0; e < NE; e++) if (e != i1 && p[e] > v2) { v2 = p[e]; i2 = e; }
        int t = t0 + tid;
        wpair[2 * t]     = v1 * inv;
        wpair[2 * t + 1] = v2 * inv;
        lp1 = atomicAdd(&ecnt[i1], 1);
        lp2 = atomicAdd(&ecnt[i2], 1);
    }
    __syncthreads();
    if (tid < NE) gbase[tid] = atomicAdd(&cnt[tid], ecnt[tid]);
    __syncthreads();
    if (tid < 64) {
        int t = t0 + tid;
        bt[i1 * T_TOK + gbase[i1] + lp1] = (u16)(2 * t);
        bt[i2 * T_TOK + gbase[i2] + lp2] = (u16)(2 * t + 1);
    }
}

// -------- 3. scatter: compact pair rows -> xg (bf16), record pos ----------
// grid 256 = e(8) x c(32); wave copies one 1KB row per iteration.
__global__ __launch_bounds__(256) void scatter_kernel(
    const float* __restrict__ x, const int* __restrict__ cnt,
    const u16* __restrict__ bt, u16* __restrict__ xg, int* __restrict__ pos)
{
    const int e = blockIdx.x & 7;
    const int c = blockIdx.x >> 3;
    const int n = cnt[e];
    const int base = prefix_base(cnt, e);
    const int wv = threadIdx.x >> 6, lane = threadIdx.x & 63;

    for (int i = c * 4 + wv; i < n; i += 128) {
        int slot = bt[e * T_TOK + i];
        const float* xr = x + (size_t)(slot >> 1) * D_IN + lane * 8;
        float4 v0 = *(const float4*)xr;
        float4 v1 = *(const float4*)(xr + 4);
        bf16x8 o;
        o[0] = (short)f32_bf16(v0.x); o[1] = (short)f32_bf16(v0.y);
        o[2] = (short)f32_bf16(v0.z); o[3] = (short)f32_bf16(v0.w);
        o[4] = (short)f32_bf16(v1.x); o[5] = (short)f32_bf16(v1.y);
        o[6] = (short)f32_bf16(v1.z); o[7] = (short)f32_bf16(v1.w);
        *(bf16x8*)&xg[(size_t)(base + i) * D_IN + lane * 8] = o;
        if (lane == 0) pos[slot] = base + i;
    }
}

// ---------------- 4. fc1 + GLU -> act (compact rows) ----------------
// grid 1024 = e(8) x ns(16) x mc(8); block 256 (4 waves), LDS 32KB -> 4 blk/CU.
// Slice: y rows [ns*16,+16) + gate rows [256+ns*16,+16). Wave tile 64x32.
// A streams sequential xg rows (affine addrs, no indirection, no barriers).
__global__ __launch_bounds__(256, 4) void fc1_kernel(
    const u16* __restrict__ xg, const u16* __restrict__ f1b,
    const int* __restrict__ cnt, u16* __restrict__ act)
{
    __shared__ __align__(16) u16 bsl[2 * 16 * 512];   // 32 KB

    const int bid = blockIdx.x;
    const int e   = bid & 7;
    const int ns  = (bid >> 3) & 15;
    const int mc  = bid >> 7;                  // 0..7
    const int n   = cnt[e];
    const int base = prefix_base(cnt, e);

    const int tid = threadIdx.x;
    const int wv  = tid >> 6, lane = tid & 63;
    const int l15 = lane & 15, lhi = lane >> 4;

    // stage slice: wave wv stages kg in [wv*4,+4) for both groups
    {
        const u16* w1 = f1b + (size_t)e * 512 * 512;
#pragma unroll
        for (int g = 0; g < 2; ++g) {
            const u16* src = w1 + (size_t)((g ? 256 : 0) + ns * 16 + l15) * 512 + lhi * 8;
#pragma unroll
            for (int k = 0; k < 4; ++k) {
                int kg = wv * 4 + k;
                GLL16(src + kg * 32, &bsl[(g * 16 + kg) * 512 + lane * 8]);
            }
        }
    }
    __syncthreads();

    for (int row0 = mc * 256; row0 < n; row0 += 2048) {
        const int rbase = row0 + wv * 64;
        if (rbase >= n) continue;
        int rm[4];
#pragma unroll
        for (int mf = 0; mf < 4; ++mf) {
            int r = rbase + mf * 16 + l15;
            rm[mf] = (r < n) ? r : (n - 1);
        }

        f32x4 acc[4][2];
#pragma unroll
        for (int mf = 0; mf < 4; ++mf) { acc[mf][0] = (f32x4)0.f; acc[mf][1] = (f32x4)0.f; }

#pragma unroll
        for (int kg = 0; kg < 16; ++kg) {
            bf16x8 a[4];
#pragma unroll
            for (int mf = 0; mf < 4; ++mf)
                a[mf] = *(const bf16x8*)&xg[(size_t)(base + rm[mf]) * D_IN + kg * 32 + lhi * 8];
            bf16x8 b0 = *(const bf16x8*)&bsl[(0 * 16 + kg) * 512 + lane * 8];
            bf16x8 b1 = *(const bf16x8*)&bsl[(1 * 16 + kg) * 512 + lane * 8];
#pragma unroll
            for (int mf = 0; mf < 4; ++mf) {
                acc[mf][0] = __builtin_amdgcn_mfma_f32_16x16x32_bf16(a[mf], b0, acc[mf][0], 0, 0, 0);
                acc[mf][1] = __builtin_amdgcn_mfma_f32_16x16x32_bf16(a[mf], b1, acc[mf][1], 0, 0, 0);
            }
        }

        // GLU + store: C frag row=lhi*4+j (token), col=l15 (fc1-col)
#pragma unroll
        for (int mf = 0; mf < 4; ++mf) {
#pragma unroll
            for (int j = 0; j < 4; ++j) {
                int rr = rbase + mf * 16 + lhi * 4 + j;
                if (rr < n) {
                    float y = acc[mf][0][j], g = acc[mf][1][j];
                    float v = y * g / (1.f + __expf(-g));
                    act[(size_t)(base + rr) * DINT + ns * 16 + l15] = f32_bf16(v);
                }
            }
        }
    }
}

// ---------------- 5. fc2 -> og (compact rows) ----------------
// grid 1024 = e(8) x ns(8: 64 out-cols) x mc(16); LDS 32KB; wave tile 32x64.
__global__ __launch_bounds__(256, 4) void fc2_kernel(
    const u16* __restrict__ act, const u16* __restrict__ f2b,
    const int* __restrict__ cnt, u16* __restrict__ og)
{
    __shared__ __align__(16) u16 bsl[4 * 8 * 512];    // 32 KB

    const int bid = blockIdx.x;
    const int e   = bid & 7;
    const int ns  = (bid >> 3) & 7;
    const int mc  = bid >> 6;                  // 0..15
    const int n   = cnt[e];
    const int base = prefix_base(cnt, e);

    const int tid = threadIdx.x;
    const int wv  = tid >> 6, lane = tid & 63;
    const int l15 = lane & 15, lhi = lane >> 4;

    {
        const u16* src = f2b + (size_t)e * D_IN * DINT
                       + (size_t)(ns * 64 + wv * 16 + l15) * DINT + lhi * 8;
#pragma unroll
        for (int kg = 0; kg < 8; ++kg)
            GLL16(src + kg * 32, &bsl[(wv * 8 + kg) * 512 + lane * 8]);
    }
    __syncthreads();

    for (int row0 = mc * 128; row0 < n; row0 += 2048) {
        const int rbase = row0 + wv * 32;
        if (rbase >= n) continue;
        int rm[2];
#pragma unroll
        for (int m = 0; m < 2; ++m) {
            int r = rbase + m * 16 + l15;
            rm[m] = (r < n) ? r : (n - 1);
        }

        f32x4 acc[2][4];
#pragma unroll
        for (int m = 0; m < 2; ++m)
#pragma unroll
            for (int g = 0; g < 4; ++g) acc[m][g] = (f32x4)0.f;

#pragma unroll
        for (int kg = 0; kg < 8; ++kg) {
            bf16x8 a0 = *(const bf16x8*)&act[(size_t)(base + rm[0]) * DINT + kg * 32 + lhi * 8];
            bf16x8 a1 = *(const bf16x8*)&act[(size_t)(base + rm[1]) * DINT + kg * 32 + lhi * 8];
#pragma unroll
            for (int g = 0; g < 4; ++g) {
                bf16x8 b = *(const bf16x8*)&bsl[(g * 8 + kg) * 512 + lane * 8];
                acc[0][g] = __builtin_amdgcn_mfma_f32_16x16x32_bf16(a0, b, acc[0][g], 0, 0, 0);
                acc[1][g] = __builtin_amdgcn_mfma_f32_16x16x32_bf16(a1, b, acc[1][g], 0, 0, 0);
            }
        }

#pragma unroll
        for (int m = 0; m < 2; ++m) {
#pragma unroll
            for (int j = 0; j < 4; ++j) {
                int rr = rbase + m * 16 + lhi * 4 + j;
                if (rr < n) {
                    u16* dst = og + (size_t)(base + rr) * D_IN + ns * 64 + l15;
#pragma unroll
                    for (int g = 0; g < 4; ++g)
                        dst[g * 16] = f32_bf16(acc[m][g][j]);
                }
            }
        }
    }
}

// ---------------- 6. combine: z[t] = w0*og[p0] + w1*og[p1] ----------------
__global__ __launch_bounds__(256) void combine_kernel(
    const u16* __restrict__ og, const int* __restrict__ pos,
    const float* __restrict__ wpair, float* __restrict__ out)
{
    int idx = blockIdx.x * 256 + threadIdx.x;
    int t  = idx >> 6;
    int c8 = (idx & 63) * 8;
    float w0 = wpair[2 * t], w1 = wpair[2 * t + 1];
    int p0 = pos[2 * t], p1 = pos[2 * t + 1];
    bf16x8 a = *(const bf16x8*)&og[(size_t)p0 * D_IN + c8];
    bf16x8 b = *(const bf16x8*)&og[(size_t)p1 * D_IN + c8];
    float4 o0, o1;
#pragma unroll
    for (int j = 0; j < 4; j++) {
        o0[j] = w0 * bf16_f32((u16)a[j])     + w1 * bf16_f32((u16)b[j]);
        o1[j] = w0 * bf16_f32((u16)a[j + 4]) + w1 * bf16_f32((u16)b[j + 4]);
    }
    float* orow = out + (size_t)t * D_IN + c8;
    *(float4*)orow = o0;
    *(float4*)(orow + 4) = o1;
}

// ---------------- launch ----------------
extern "C" void kernel_launch(void* const* d_in, const int* in_sizes, int n_in,
                              void* d_out, int out_size, void* d_ws, size_t ws_size,
                              hipStream_t stream) {
    const float* x   = (const float*)d_in[0];
    const float* wg  = (const float*)d_in[1];
    const float* fc1 = (const float*)d_in[2];
    const float* fc2 = (const float*)d_in[3];
    float* out = (float*)d_out;
    char* ws = (char*)d_ws;

    int*   cnt   = (int*)(ws + WS_CNT);
    int*   pos   = (int*)(ws + WS_POS);
    float* wpair = (float*)(ws + WS_WP);
    u16*   bt    = (u16*)(ws + WS_BT);
    u16*   f2b   = (u16*)(ws + WS_F2B);
    u16*   aact  = (u16*)(ws + WS_AA);
    u16*   f1b   = (u16*)(ws + WS_F1B);
    u16*   xg    = (u16*)(ws + WS_XG);
    u16*   og    = (u16*)(ws + WS_OG);

    hipMemsetAsync(cnt, 0, 1024, stream);

    cvt_kernel<<<1024, 256, 0, stream>>>(fc1, fc2, f1b, f2b);
    gate_kernel<<<T_TOK / 64, 256, 0, stream>>>(x, wg, cnt, bt, wpair);
    scatter_kernel<<<256, 256, 0, stream>>>(x, cnt, bt, xg, pos);
    fc1_kernel<<<1024, 256, 0, stream>>>(xg, f1b, cnt, aact);
    fc2_kernel<<<1024, 256, 0, stream>>>(aact, f2b, cnt, og);
    combine_kernel<<<T_TOK * (D_IN / 8) / 256, 256, 0, stream>>>(og, pos, wpair, out);
}

// Round 8
// 93.554 us; speedup vs baseline: 1.7816x; 1.2486x over previous
//
#include <hip/hip_runtime.h>
#include <hip/hip_bf16.h>
#include <stdint.h>

#define T_TOK 8192
#define D_IN  512
#define DINT  256
#define NE    8

typedef float f32x4 __attribute__((ext_vector_type(4)));
typedef short bf16x8 __attribute__((ext_vector_type(8)));
typedef unsigned short u16;
typedef unsigned short u16x4 __attribute__((ext_vector_type(4)));

// ws layout (bytes). og overlays xb+f1b (+pad): both dead before fc2 writes og.
#define WS_CNT   0                 // int[8]
#define WS_WP    1024              // f32[16384]         -> 66560
#define WS_BT    66560             // u16[8][8192]       -> 197632
#define WS_F2B   197632            // bf16 fc2 (2MB)     -> 2294784
#define WS_AA    2294784           // bf16 act [16384][256] (8MB) -> 10683392
#define WS_XB    10683392          // bf16 xb [8192][512] (8MB)   -> 19072000
#define WS_F1B   19072000          // bf16 fc1 (4MB)     -> 23266304
#define WS_OG    WS_XB             // bf16 og [16384][512] (16MB) -> 27460608

typedef const __attribute__((address_space(1))) void* gptr_t;
typedef __attribute__((address_space(3))) void* lptr_t;
#define GLL16(g, s) __builtin_amdgcn_global_load_lds((gptr_t)(g), (lptr_t)(s), 16, 0, 0)

static __device__ __forceinline__ u16 f32_bf16(float f) {
    union { float f; uint32_t u; } v; v.f = f;
    uint32_t u = v.u;
    uint32_t r = (u + 0x7FFFu + ((u >> 16) & 1u)) >> 16;   // RTNE
    return (u16)r;
}
static __device__ __forceinline__ float bf16_f32(u16 h) {
    union { uint32_t u; float f; } v; v.u = ((uint32_t)h) << 16; return v.f;
}

// ---------------- 1. f32 -> bf16 of fc1, fc2 ----------------
__global__ __launch_bounds__(256) void cvt_kernel(
    const float* __restrict__ fc1, const float* __restrict__ fc2,
    u16* __restrict__ f1b, u16* __restrict__ f2b)
{
    const int N1 = NE * 2 * DINT * D_IN / 4;
    const int N2 = NE * D_IN * DINT / 4;
    const int total = N1 + N2;
    for (int i = blockIdx.x * 256 + threadIdx.x; i < total; i += gridDim.x * 256) {
        const float4* s; u16* d; int j;
        if (i < N1) { s = (const float4*)fc1; d = f1b; j = i; }
        else        { s = (const float4*)fc2; d = f2b; j = i - N1; }
        float4 v = s[j];
        u16x4 o;
        o.x = f32_bf16(v.x); o.y = f32_bf16(v.y);
        o.z = f32_bf16(v.z); o.w = f32_bf16(v.w);
        *(u16x4*)&d[(size_t)j * 4] = o;
    }
}

// ------- 2. gate: x -> xb (bf16), logits, softmax, top-2, buckets ----------
__global__ __launch_bounds__(256) void gate_kernel(
    const float* __restrict__ x, const float* __restrict__ wg,
    int* __restrict__ cnt, u16* __restrict__ bt, float* __restrict__ wpair,
    u16* __restrict__ xb)
{
    __shared__ float wgl[NE * D_IN];
    __shared__ float xt[64][67];
    __shared__ float part[256 * 9];
    __shared__ int ecnt[NE];
    __shared__ int gbase[NE];

    const int tid = threadIdx.x;
    const int t0  = blockIdx.x * 64;
    const int tl  = tid & 63;
    const int kq  = tid >> 6;

    for (int i = tid; i < NE * D_IN; i += 256) wgl[i] = wg[i];
    if (tid < NE) ecnt[tid] = 0;

    float acc[NE];
#pragma unroll
    for (int e = 0; e < NE; e++) acc[e] = 0.f;

    for (int c = 0; c < 8; ++c) {
        __syncthreads();
#pragma unroll
        for (int i = 0; i < 4; ++i) {
            int idx = i * 256 + tid;
            int row = idx >> 4, c4 = idx & 15;
            float4 v = *(const float4*)&x[(size_t)(t0 + row) * D_IN + c * 64 + c4 * 4];
            u16x4 o;
            o.x = f32_bf16(v.x); o.y = f32_bf16(v.y);
            o.z = f32_bf16(v.z); o.w = f32_bf16(v.w);
            *(u16x4*)&xb[(size_t)(t0 + row) * D_IN + c * 64 + c4 * 4] = o;
            xt[c4 * 4 + 0][row] = v.x; xt[c4 * 4 + 1][row] = v.y;
            xt[c4 * 4 + 2][row] = v.z; xt[c4 * 4 + 3][row] = v.w;
        }
        __syncthreads();
#pragma unroll
        for (int j = 0; j < 16; ++j) {
            float xv = xt[kq * 16 + j][tl];
#pragma unroll
            for (int e = 0; e < NE; e++)
                acc[e] = fmaf(xv, wgl[e * D_IN + c * 64 + kq * 16 + j], acc[e]);
        }
    }
#pragma unroll
    for (int e = 0; e < NE; e++) part[tid * 9 + e] = acc[e];
    __syncthreads();

    int i1 = 0, i2 = -1, lp1 = 0, lp2 = 0;
    if (tid < 64) {
        float s8[NE];
#pragma unroll
        for (int e = 0; e < NE; e++)
            s8[e] = part[tid * 9 + e] + part[(64 + tid) * 9 + e]
                  + part[(128 + tid) * 9 + e] + part[(192 + tid) * 9 + e];
        float m = s8[0];
#pragma unroll
        for (int e = 1; e < NE; e++) m = fmaxf(m, s8[e]);
        float p[NE], s = 0.f;
#pragma unroll
        for (int e = 0; e < NE; e++) { p[e] = expf(s8[e] - m); s += p[e]; }
        float inv = 1.f / s;
        float v1 = p[0];
#pragma unroll
        for (int e = 1; e < NE; e++) if (p[e] > v1) { v1 = p[e]; i1 = e; }
        float v2 = -1.f;
#pragma unroll
        for (int e = 0; e < NE; e++) if (e != i1 && p[e] > v2) { v2 = p[e]; i2 = e; }
        int t = t0 + tid;
        wpair[2 * t]     = v1 * inv;
        wpair[2 * t + 1] = v2 * inv;
        lp1 = atomicAdd(&ecnt[i1], 1);
        lp2 = atomicAdd(&ecnt[i2], 1);
    }
    __syncthreads();
    if (tid < NE) gbase[tid] = atomicAdd(&cnt[tid], ecnt[tid]);
    __syncthreads();
    if (tid < 64) {
        int t = t0 + tid;
        bt[i1 * T_TOK + gbase[i1] + lp1] = (u16)(2 * t);
        bt[i2 * T_TOK + gbase[i2] + lp2] = (u16)(2 * t + 1);
    }
}

// ---------------- 3. fc1 + GLU -> act (slot-indexed) ----------------
// m97 replica: 128x128 tile, 4 waves (2x2), BK=32, A+B both GLL16-staged into
// 16KB single-buffered LDS, 2 barriers/step, ~3 blocks/CU for drain overlap.
// N-panel = 64 y-cols [nt*64,+64) + matching gate-cols [256+nt*64,+64).
__global__ __launch_bounds__(256) void fc1_kernel(
    const u16* __restrict__ xb, const u16* __restrict__ f1b,
    const int* __restrict__ cnt, const u16* __restrict__ bt,
    u16* __restrict__ act)
{
    __shared__ __align__(16) u16 asl[8 * 512];   // 8KB: A frag f at f*512, lane*8
    __shared__ __align__(16) u16 bsl[8 * 512];   // 8KB: [y0 y1 y2 y3 g0 g1 g2 g3]
    __shared__ u16 slot_l[128];

    const int bid = blockIdx.x;
    const int e   = bid & 7;                     // XCD pinning
    const int nt  = (bid >> 3) & 3;
    const int mt  = bid >> 5;                    // 0..63
    const int n   = cnt[e];
    const int row0 = mt * 128;
    if (row0 >= n) return;

    const int tid = threadIdx.x;
    const int wv  = tid >> 6, lane = tid & 63;
    const int l15 = lane & 15, lhi = lane >> 4;
    const int wr  = wv >> 1, wc = wv & 1;

    if (tid < 128) {
        int r = row0 + tid;
        slot_l[tid] = bt[e * T_TOK + ((r < n) ? r : (n - 1))];
    }
    __syncthreads();

    // staging sources: wave wv owns A frags {2wv,2wv+1}, B frags {2wv,2wv+1}
    const u16* srcA0 = xb + (size_t)(slot_l[(wv * 2 + 0) * 16 + l15] >> 1) * D_IN + lhi * 8;
    const u16* srcA1 = xb + (size_t)(slot_l[(wv * 2 + 1) * 16 + l15] >> 1) * D_IN + lhi * 8;
    const u16* w1 = f1b + (size_t)e * 512 * 512;
    const int fb0 = wv * 2, fb1 = wv * 2 + 1;
    const int rB0 = ((fb0 < 4) ? (nt * 64 + fb0 * 16) : (256 + nt * 64 + (fb0 - 4) * 16)) + l15;
    const int rB1 = ((fb1 < 4) ? (nt * 64 + fb1 * 16) : (256 + nt * 64 + (fb1 - 4) * 16)) + l15;
    const u16* srcB0 = w1 + (size_t)rB0 * 512 + lhi * 8;
    const u16* srcB1 = w1 + (size_t)rB1 * 512 + lhi * 8;

    f32x4 acc[4][4];
#pragma unroll
    for (int m = 0; m < 4; m++)
#pragma unroll
        for (int nb = 0; nb < 4; nb++) acc[m][nb] = (f32x4)0.f;

    for (int k0 = 0; k0 < 512; k0 += 32) {
        GLL16(srcA0 + k0, &asl[fb0 * 512]);
        GLL16(srcA1 + k0, &asl[fb1 * 512]);
        GLL16(srcB0 + k0, &bsl[fb0 * 512]);
        GLL16(srcB1 + k0, &bsl[fb1 * 512]);
        __syncthreads();                         // staging complete
        bf16x8 a[4], b[4];
#pragma unroll
        for (int m = 0; m < 4; m++)
            a[m] = *(const bf16x8*)&asl[(wr * 4 + m) * 512 + lane * 8];
        b[0] = *(const bf16x8*)&bsl[(wc * 2 + 0) * 512 + lane * 8];
        b[1] = *(const bf16x8*)&bsl[(wc * 2 + 1) * 512 + lane * 8];
        b[2] = *(const bf16x8*)&bsl[(4 + wc * 2 + 0) * 512 + lane * 8];
        b[3] = *(const bf16x8*)&bsl[(4 + wc * 2 + 1) * 512 + lane * 8];
#pragma unroll
        for (int m = 0; m < 4; m++)
#pragma unroll
            for (int nb = 0; nb < 4; nb++)
                acc[m][nb] = __builtin_amdgcn_mfma_f32_16x16x32_bf16(
                    a[m], b[nb], acc[m][nb], 0, 0, 0);
        __syncthreads();                         // reads done before next stage
    }

    // GLU + store: acc[m][q]=y, acc[m][q+2]=gate, same output col
#pragma unroll
    for (int m = 0; m < 4; m++) {
#pragma unroll
        for (int j = 0; j < 4; j++) {
            int lrow = wr * 64 + m * 16 + lhi * 4 + j;
            if (row0 + lrow < n) {
                int slot = slot_l[lrow];
#pragma unroll
                for (int q = 0; q < 2; q++) {
                    float y = acc[m][q][j], g = acc[m][q + 2][j];
                    float v = y * g / (1.f + __expf(-g));
                    act[(size_t)slot * DINT + nt * 64 + wc * 32 + q * 16 + l15] = f32_bf16(v);
                }
            }
        }
    }
}

// ---------------- 4. fc2 -> og (slot-indexed) ----------------
__global__ __launch_bounds__(256) void fc2_kernel(
    const u16* __restrict__ act, const u16* __restrict__ f2b,
    const int* __restrict__ cnt, const u16* __restrict__ bt,
    u16* __restrict__ og)
{
    __shared__ __align__(16) u16 asl[8 * 512];
    __shared__ __align__(16) u16 bsl[8 * 512];
    __shared__ u16 slot_l[128];

    const int bid = blockIdx.x;
    const int e   = bid & 7;
    const int nt  = (bid >> 3) & 3;
    const int mt  = bid >> 5;
    const int n   = cnt[e];
    const int row0 = mt * 128;
    if (row0 >= n) return;

    const int tid = threadIdx.x;
    const int wv  = tid >> 6, lane = tid & 63;
    const int l15 = lane & 15, lhi = lane >> 4;
    const int wr  = wv >> 1, wc = wv & 1;

    if (tid < 128) {
        int r = row0 + tid;
        slot_l[tid] = bt[e * T_TOK + ((r < n) ? r : (n - 1))];
    }
    __syncthreads();

    const u16* srcA0 = act + (size_t)slot_l[(wv * 2 + 0) * 16 + l15] * DINT + lhi * 8;
    const u16* srcA1 = act + (size_t)slot_l[(wv * 2 + 1) * 16 + l15] * DINT + lhi * 8;
    const u16* w2 = f2b + (size_t)e * D_IN * DINT;
    const int fb0 = wv * 2, fb1 = wv * 2 + 1;
    const u16* srcB0 = w2 + (size_t)(nt * 128 + fb0 * 16 + l15) * DINT + lhi * 8;
    const u16* srcB1 = w2 + (size_t)(nt * 128 + fb1 * 16 + l15) * DINT + lhi * 8;

    f32x4 acc[4][4];
#pragma unroll
    for (int m = 0; m < 4; m++)
#pragma unroll
        for (int nb = 0; nb < 4; nb++) acc[m][nb] = (f32x4)0.f;

    for (int k0 = 0; k0 < 256; k0 += 32) {
        GLL16(srcA0 + k0, &asl[fb0 * 512]);
        GLL16(srcA1 + k0, &asl[fb1 * 512]);
        GLL16(srcB0 + k0, &bsl[fb0 * 512]);
        GLL16(srcB1 + k0, &bsl[fb1 * 512]);
        __syncthreads();
        bf16x8 a[4], b[4];
#pragma unroll
        for (int m = 0; m < 4; m++)
            a[m] = *(const bf16x8*)&asl[(wr * 4 + m) * 512 + lane * 8];
#pragma unroll
        for (int nb = 0; nb < 4; nb++)
            b[nb] = *(const bf16x8*)&bsl[(wc * 4 + nb) * 512 + lane * 8];
#pragma unroll
        for (int m = 0; m < 4; m++)
#pragma unroll
            for (int nb = 0; nb < 4; nb++)
                acc[m][nb] = __builtin_amdgcn_mfma_f32_16x16x32_bf16(
                    a[m], b[nb], acc[m][nb], 0, 0, 0);
        __syncthreads();
    }

#pragma unroll
    for (int m = 0; m < 4; m++) {
#pragma unroll
        for (int j = 0; j < 4; j++) {
            int lrow = wr * 64 + m * 16 + lhi * 4 + j;
            if (row0 + lrow < n) {
                int slot = slot_l[lrow];
                u16* dst = og + (size_t)slot * D_IN + nt * 128 + wc * 64 + l15;
#pragma unroll
                for (int nb = 0; nb < 4; nb++)
                    dst[nb * 16] = f32_bf16(acc[m][nb][j]);
            }
        }
    }
}

// ---------------- 5. combine: z[t] = w0*og[2t] + w1*og[2t+1] ----------------
__global__ __launch_bounds__(256) void combine_kernel(
    const u16* __restrict__ og, const float* __restrict__ wpair,
    float* __restrict__ out)
{
    int idx = blockIdx.x * 256 + threadIdx.x;
    int t  = idx >> 6;
    int c8 = (idx & 63) * 8;
    float w0 = wpair[2 * t], w1 = wpair[2 * t + 1];
    bf16x8 a = *(const bf16x8*)&og[(size_t)(2 * t) * D_IN + c8];
    bf16x8 b = *(const bf16x8*)&og[(size_t)(2 * t + 1) * D_IN + c8];
    float4 o0, o1;
#pragma unroll
    for (int j = 0; j < 4; j++) {
        o0[j] = w0 * bf16_f32((u16)a[j])     + w1 * bf16_f32((u16)b[j]);
        o1[j] = w0 * bf16_f32((u16)a[j + 4]) + w1 * bf16_f32((u16)b[j + 4]);
    }
    float* orow = out + (size_t)t * D_IN + c8;
    *(float4*)orow = o0;
    *(float4*)(orow + 4) = o1;
}

// ---------------- launch ----------------
extern "C" void kernel_launch(void* const* d_in, const int* in_sizes, int n_in,
                              void* d_out, int out_size, void* d_ws, size_t ws_size,
                              hipStream_t stream) {
    const float* x   = (const float*)d_in[0];
    const float* wg  = (const float*)d_in[1];
    const float* fc1 = (const float*)d_in[2];
    const float* fc2 = (const float*)d_in[3];
    float* out = (float*)d_out;
    char* ws = (char*)d_ws;

    int*   cnt   = (int*)(ws + WS_CNT);
    float* wpair = (float*)(ws + WS_WP);
    u16*   bt    = (u16*)(ws + WS_BT);
    u16*   f2b   = (u16*)(ws + WS_F2B);
    u16*   aact  = (u16*)(ws + WS_AA);
    u16*   xb    = (u16*)(ws + WS_XB);
    u16*   f1b   = (u16*)(ws + WS_F1B);
    u16*   og    = (u16*)(ws + WS_OG);

    hipMemsetAsync(cnt, 0, 1024, stream);

    cvt_kernel<<<1024, 256, 0, stream>>>(fc1, fc2, f1b, f2b);
    gate_kernel<<<T_TOK / 64, 256, 0, stream>>>(x, wg, cnt, bt, wpair, xb);
    fc1_kernel<<<2048, 256, 0, stream>>>(xb, f1b, cnt, bt, aact);
    fc2_kernel<<<2048, 256, 0, stream>>>(aact, f2b, cnt, bt, og);
    combine_kernel<<<T_TOK * (D_IN / 8) / 256, 256, 0, stream>>>(og, wpair, out);
}

// Round 9
// 88.835 us; speedup vs baseline: 1.8762x; 1.0531x over previous
//
#include <hip/hip_runtime.h>
#include <hip/hip_bf16.h>
#include <stdint.h>

#define T_TOK 8192
#define D_IN  512
#define DINT  256
#define NE    8

typedef float f32x4 __attribute__((ext_vector_type(4)));
typedef short bf16x8 __attribute__((ext_vector_type(8)));
typedef unsigned short u16;
typedef unsigned short u16x4 __attribute__((ext_vector_type(4)));

// ws layout (bytes). og overlays xb+f1b (+pad): both dead before fc2 writes og.
#define WS_CNT   0                 // int[8]
#define WS_WP    1024              // f32[16384]         -> 66560
#define WS_BT    66560             // u16[8][8192]       -> 197632
#define WS_F2B   197632            // bf16 fc2 (2MB)     -> 2294784
#define WS_AA    2294784           // bf16 act [16384][256] (8MB) -> 10683392
#define WS_XB    10683392          // bf16 xb [8192][512] (8MB)   -> 19072000
#define WS_F1B   19072000          // bf16 fc1 (4MB)     -> 23266304
#define WS_OG    WS_XB             // bf16 og [16384][512] (16MB) -> 27460608

typedef const __attribute__((address_space(1))) void* gptr_t;
typedef __attribute__((address_space(3))) void* lptr_t;
#define GLL16(g, s) __builtin_amdgcn_global_load_lds((gptr_t)(g), (lptr_t)(s), 16, 0, 0)

static __device__ __forceinline__ u16 f32_bf16(float f) {
    union { float f; uint32_t u; } v; v.f = f;
    uint32_t u = v.u;
    uint32_t r = (u + 0x7FFFu + ((u >> 16) & 1u)) >> 16;   // RTNE
    return (u16)r;
}
static __device__ __forceinline__ float bf16_f32(u16 h) {
    union { uint32_t u; float f; } v; v.u = ((uint32_t)h) << 16; return v.f;
}

// ------- 1. f32 -> bf16 of fc1, fc2; block 0 zeroes cnt (pre-gate) ---------
__global__ __launch_bounds__(256) void cvt_kernel(
    const float* __restrict__ fc1, const float* __restrict__ fc2,
    u16* __restrict__ f1b, u16* __restrict__ f2b, int* __restrict__ cnt)
{
    if (blockIdx.x == 0 && threadIdx.x < NE) cnt[threadIdx.x] = 0;
    const int N1 = NE * 2 * DINT * D_IN / 4;
    const int N2 = NE * D_IN * DINT / 4;
    const int total = N1 + N2;
    for (int i = blockIdx.x * 256 + threadIdx.x; i < total; i += gridDim.x * 256) {
        const float4* s; u16* d; int j;
        if (i < N1) { s = (const float4*)fc1; d = f1b; j = i; }
        else        { s = (const float4*)fc2; d = f2b; j = i - N1; }
        float4 v = s[j];
        u16x4 o;
        o.x = f32_bf16(v.x); o.y = f32_bf16(v.y);
        o.z = f32_bf16(v.z); o.w = f32_bf16(v.w);
        *(u16x4*)&d[(size_t)j * 4] = o;
    }
}

// ------- 2. gate: x -> xb (bf16), logits, softmax, top-2, buckets ----------
__global__ __launch_bounds__(256) void gate_kernel(
    const float* __restrict__ x, const float* __restrict__ wg,
    int* __restrict__ cnt, u16* __restrict__ bt, float* __restrict__ wpair,
    u16* __restrict__ xb)
{
    __shared__ float wgl[NE * D_IN];
    __shared__ float xt[64][67];
    __shared__ float part[256 * 9];
    __shared__ int ecnt[NE];
    __shared__ int gbase[NE];

    const int tid = threadIdx.x;
    const int t0  = blockIdx.x * 64;
    const int tl  = tid & 63;
    const int kq  = tid >> 6;

    for (int i = tid; i < NE * D_IN; i += 256) wgl[i] = wg[i];
    if (tid < NE) ecnt[tid] = 0;

    float acc[NE];
#pragma unroll
    for (int e = 0; e < NE; e++) acc[e] = 0.f;

    for (int c = 0; c < 8; ++c) {
        __syncthreads();
#pragma unroll
        for (int i = 0; i < 4; ++i) {
            int idx = i * 256 + tid;
            int row = idx >> 4, c4 = idx & 15;
            float4 v = *(const float4*)&x[(size_t)(t0 + row) * D_IN + c * 64 + c4 * 4];
            u16x4 o;
            o.x = f32_bf16(v.x); o.y = f32_bf16(v.y);
            o.z = f32_bf16(v.z); o.w = f32_bf16(v.w);
            *(u16x4*)&xb[(size_t)(t0 + row) * D_IN + c * 64 + c4 * 4] = o;
            xt[c4 * 4 + 0][row] = v.x; xt[c4 * 4 + 1][row] = v.y;
            xt[c4 * 4 + 2][row] = v.z; xt[c4 * 4 + 3][row] = v.w;
        }
        __syncthreads();
#pragma unroll
        for (int j = 0; j < 16; ++j) {
            float xv = xt[kq * 16 + j][tl];
#pragma unroll
            for (int e = 0; e < NE; e++)
                acc[e] = fmaf(xv, wgl[e * D_IN + c * 64 + kq * 16 + j], acc[e]);
        }
    }
#pragma unroll
    for (int e = 0; e < NE; e++) part[tid * 9 + e] = acc[e];
    __syncthreads();

    int i1 = 0, i2 = -1, lp1 = 0, lp2 = 0;
    if (tid < 64) {
        float s8[NE];
#pragma unroll
        for (int e = 0; e < NE; e++)
            s8[e] = part[tid * 9 + e] + part[(64 + tid) * 9 + e]
                  + part[(128 + tid) * 9 + e] + part[(192 + tid) * 9 + e];
        float m = s8[0];
#pragma unroll
        for (int e = 1; e < NE; e++) m = fmaxf(m, s8[e]);
        float p[NE], s = 0.f;
#pragma unroll
        for (int e = 0; e < NE; e++) { p[e] = expf(s8[e] - m); s += p[e]; }
        float inv = 1.f / s;
        float v1 = p[0];
#pragma unroll
        for (int e = 1; e < NE; e++) if (p[e] > v1) { v1 = p[e]; i1 = e; }
        float v2 = -1.f;
#pragma unroll
        for (int e = 0; e < NE; e++) if (e != i1 && p[e] > v2) { v2 = p[e]; i2 = e; }
        int t = t0 + tid;
        wpair[2 * t]     = v1 * inv;
        wpair[2 * t + 1] = v2 * inv;
        lp1 = atomicAdd(&ecnt[i1], 1);
        lp2 = atomicAdd(&ecnt[i2], 1);
    }
    __syncthreads();
    if (tid < NE) gbase[tid] = atomicAdd(&cnt[tid], ecnt[tid]);
    __syncthreads();
    if (tid < 64) {
        int t = t0 + tid;
        bt[i1 * T_TOK + gbase[i1] + lp1] = (u16)(2 * t);
        bt[i2 * T_TOK + gbase[i2] + lp2] = (u16)(2 * t + 1);
    }
}

// ---------------- 3. fc1 + GLU -> act (slot-indexed) ----------------
// m97 replica: 128x128 tile, 4 waves (2x2), BK=32, A+B both GLL16-staged into
// 16KB single-buffered LDS, 2 barriers/step, ~3 blocks/CU for drain overlap.
// N-panel = 64 y-cols [nt*64,+64) + matching gate-cols [256+nt*64,+64).
__global__ __launch_bounds__(256) void fc1_kernel(
    const u16* __restrict__ xb, const u16* __restrict__ f1b,
    const int* __restrict__ cnt, const u16* __restrict__ bt,
    u16* __restrict__ act)
{
    __shared__ __align__(16) u16 asl[8 * 512];   // 8KB: A frag f at f*512, lane*8
    __shared__ __align__(16) u16 bsl[8 * 512];   // 8KB: [y0 y1 y2 y3 g0 g1 g2 g3]
    __shared__ u16 slot_l[128];

    const int bid = blockIdx.x;
    const int e   = bid & 7;                     // XCD pinning
    const int nt  = (bid >> 3) & 3;
    const int mt  = bid >> 5;                    // 0..63
    const int n   = cnt[e];
    const int row0 = mt * 128;
    if (row0 >= n) return;

    const int tid = threadIdx.x;
    const int wv  = tid >> 6, lane = tid & 63;
    const int l15 = lane & 15, lhi = lane >> 4;
    const int wr  = wv >> 1, wc = wv & 1;

    if (tid < 128) {
        int r = row0 + tid;
        slot_l[tid] = bt[e * T_TOK + ((r < n) ? r : (n - 1))];
    }
    __syncthreads();

    // staging sources: wave wv owns A frags {2wv,2wv+1}, B frags {2wv,2wv+1}
    const u16* srcA0 = xb + (size_t)(slot_l[(wv * 2 + 0) * 16 + l15] >> 1) * D_IN + lhi * 8;
    const u16* srcA1 = xb + (size_t)(slot_l[(wv * 2 + 1) * 16 + l15] >> 1) * D_IN + lhi * 8;
    const u16* w1 = f1b + (size_t)e * 512 * 512;
    const int fb0 = wv * 2, fb1 = wv * 2 + 1;
    const int rB0 = ((fb0 < 4) ? (nt * 64 + fb0 * 16) : (256 + nt * 64 + (fb0 - 4) * 16)) + l15;
    const int rB1 = ((fb1 < 4) ? (nt * 64 + fb1 * 16) : (256 + nt * 64 + (fb1 - 4) * 16)) + l15;
    const u16* srcB0 = w1 + (size_t)rB0 * 512 + lhi * 8;
    const u16* srcB1 = w1 + (size_t)rB1 * 512 + lhi * 8;

    f32x4 acc[4][4];
#pragma unroll
    for (int m = 0; m < 4; m++)
#pragma unroll
        for (int nb = 0; nb < 4; nb++) acc[m][nb] = (f32x4)0.f;

    for (int k0 = 0; k0 < 512; k0 += 32) {
        GLL16(srcA0 + k0, &asl[fb0 * 512]);
        GLL16(srcA1 + k0, &asl[fb1 * 512]);
        GLL16(srcB0 + k0, &bsl[fb0 * 512]);
        GLL16(srcB1 + k0, &bsl[fb1 * 512]);
        __syncthreads();                         // staging complete
        bf16x8 a[4], b[4];
#pragma unroll
        for (int m = 0; m < 4; m++)
            a[m] = *(const bf16x8*)&asl[(wr * 4 + m) * 512 + lane * 8];
        b[0] = *(const bf16x8*)&bsl[(wc * 2 + 0) * 512 + lane * 8];
        b[1] = *(const bf16x8*)&bsl[(wc * 2 + 1) * 512 + lane * 8];
        b[2] = *(const bf16x8*)&bsl[(4 + wc * 2 + 0) * 512 + lane * 8];
        b[3] = *(const bf16x8*)&bsl[(4 + wc * 2 + 1) * 512 + lane * 8];
#pragma unroll
        for (int m = 0; m < 4; m++)
#pragma unroll
            for (int nb = 0; nb < 4; nb++)
                acc[m][nb] = __builtin_amdgcn_mfma_f32_16x16x32_bf16(
                    a[m], b[nb], acc[m][nb], 0, 0, 0);
        __syncthreads();                         // reads done before next stage
    }

    // GLU + store: acc[m][q]=y, acc[m][q+2]=gate, same output col
#pragma unroll
    for (int m = 0; m < 4; m++) {
#pragma unroll
        for (int j = 0; j < 4; j++) {
            int lrow = wr * 64 + m * 16 + lhi * 4 + j;
            if (row0 + lrow < n) {
                int slot = slot_l[lrow];
#pragma unroll
                for (int q = 0; q < 2; q++) {
                    float y = acc[m][q][j], g = acc[m][q + 2][j];
                    float v = y * g / (1.f + __expf(-g));
                    act[(size_t)slot * DINT + nt * 64 + wc * 32 + q * 16 + l15] = f32_bf16(v);
                }
            }
        }
    }
}

// ---------------- 4. fc2 -> og (slot-indexed) ----------------
__global__ __launch_bounds__(256) void fc2_kernel(
    const u16* __restrict__ act, const u16* __restrict__ f2b,
    const int* __restrict__ cnt, const u16* __restrict__ bt,
    u16* __restrict__ og)
{
    __shared__ __align__(16) u16 asl[8 * 512];
    __shared__ __align__(16) u16 bsl[8 * 512];
    __shared__ u16 slot_l[128];

    const int bid = blockIdx.x;
    const int e   = bid & 7;
    const int nt  = (bid >> 3) & 3;
    const int mt  = bid >> 5;
    const int n   = cnt[e];
    const int row0 = mt * 128;
    if (row0 >= n) return;

    const int tid = threadIdx.x;
    const int wv  = tid >> 6, lane = tid & 63;
    const int l15 = lane & 15, lhi = lane >> 4;
    const int wr  = wv >> 1, wc = wv & 1;

    if (tid < 128) {
        int r = row0 + tid;
        slot_l[tid] = bt[e * T_TOK + ((r < n) ? r : (n - 1))];
    }
    __syncthreads();

    const u16* srcA0 = act + (size_t)slot_l[(wv * 2 + 0) * 16 + l15] * DINT + lhi * 8;
    const u16* srcA1 = act + (size_t)slot_l[(wv * 2 + 1) * 16 + l15] * DINT + lhi * 8;
    const u16* w2 = f2b + (size_t)e * D_IN * DINT;
    const int fb0 = wv * 2, fb1 = wv * 2 + 1;
    const u16* srcB0 = w2 + (size_t)(nt * 128 + fb0 * 16 + l15) * DINT + lhi * 8;
    const u16* srcB1 = w2 + (size_t)(nt * 128 + fb1 * 16 + l15) * DINT + lhi * 8;

    f32x4 acc[4][4];
#pragma unroll
    for (int m = 0; m < 4; m++)
#pragma unroll
        for (int nb = 0; nb < 4; nb++) acc[m][nb] = (f32x4)0.f;

    for (int k0 = 0; k0 < 256; k0 += 32) {
        GLL16(srcA0 + k0, &asl[fb0 * 512]);
        GLL16(srcA1 + k0, &asl[fb1 * 512]);
        GLL16(srcB0 + k0, &bsl[fb0 * 512]);
        GLL16(srcB1 + k0, &bsl[fb1 * 512]);
        __syncthreads();
        bf16x8 a[4], b[4];
#pragma unroll
        for (int m = 0; m < 4; m++)
            a[m] = *(const bf16x8*)&asl[(wr * 4 + m) * 512 + lane * 8];
#pragma unroll
        for (int nb = 0; nb < 4; nb++)
            b[nb] = *(const bf16x8*)&bsl[(wc * 4 + nb) * 512 + lane * 8];
#pragma unroll
        for (int m = 0; m < 4; m++)
#pragma unroll
            for (int nb = 0; nb < 4; nb++)
                acc[m][nb] = __builtin_amdgcn_mfma_f32_16x16x32_bf16(
                    a[m], b[nb], acc[m][nb], 0, 0, 0);
        __syncthreads();
    }

#pragma unroll
    for (int m = 0; m < 4; m++) {
#pragma unroll
        for (int j = 0; j < 4; j++) {
            int lrow = wr * 64 + m * 16 + lhi * 4 + j;
            if (row0 + lrow < n) {
                int slot = slot_l[lrow];
                u16* dst = og + (size_t)slot * D_IN + nt * 128 + wc * 64 + l15;
#pragma unroll
                for (int nb = 0; nb < 4; nb++)
                    dst[nb * 16] = f32_bf16(acc[m][nb][j]);
            }
        }
    }
}

// ---------------- 5. combine: z[t] = w0*og[2t] + w1*og[2t+1] ----------------
__global__ __launch_bounds__(256) void combine_kernel(
    const u16* __restrict__ og, const float* __restrict__ wpair,
    float* __restrict__ out)
{
    int idx = blockIdx.x * 256 + threadIdx.x;
    int t  = idx >> 6;
    int c8 = (idx & 63) * 8;
    float w0 = wpair[2 * t], w1 = wpair[2 * t + 1];
    bf16x8 a = *(const bf16x8*)&og[(size_t)(2 * t) * D_IN + c8];
    bf16x8 b = *(const bf16x8*)&og[(size_t)(2 * t + 1) * D_IN + c8];
    float4 o0, o1;
#pragma unroll
    for (int j = 0; j < 4; j++) {
        o0[j] = w0 * bf16_f32((u16)a[j])     + w1 * bf16_f32((u16)b[j]);
        o1[j] = w0 * bf16_f32((u16)a[j + 4]) + w1 * bf16_f32((u16)b[j + 4]);
    }
    float* orow = out + (size_t)t * D_IN + c8;
    *(float4*)orow = o0;
    *(float4*)(orow + 4) = o1;
}

// ---------------- launch ----------------
extern "C" void kernel_launch(void* const* d_in, const int* in_sizes, int n_in,
                              void* d_out, int out_size, void* d_ws, size_t ws_size,
                              hipStream_t stream) {
    const float* x   = (const float*)d_in[0];
    const float* wg  = (const float*)d_in[1];
    const float* fc1 = (const float*)d_in[2];
    const float* fc2 = (const float*)d_in[3];
    float* out = (float*)d_out;
    char* ws = (char*)d_ws;

    int*   cnt   = (int*)(ws + WS_CNT);
    float* wpair = (float*)(ws + WS_WP);
    u16*   bt    = (u16*)(ws + WS_BT);
    u16*   f2b   = (u16*)(ws + WS_F2B);
    u16*   aact  = (u16*)(ws + WS_AA);
    u16*   xb    = (u16*)(ws + WS_XB);
    u16*   f1b   = (u16*)(ws + WS_F1B);
    u16*   og    = (u16*)(ws + WS_OG);

    cvt_kernel<<<1024, 256, 0, stream>>>(fc1, fc2, f1b, f2b, cnt);
    gate_kernel<<<T_TOK / 64, 256, 0, stream>>>(x, wg, cnt, bt, wpair, xb);
    fc1_kernel<<<2048, 256, 0, stream>>>(xb, f1b, cnt, bt, aact);
    fc2_kernel<<<2048, 256, 0, stream>>>(aact, f2b, cnt, bt, og);
    combine_kernel<<<T_TOK * (D_IN / 8) / 256, 256, 0, stream>>>(og, wpair, out);
}